// Round 15
// baseline (235.933 us; speedup 1.0000x reference)
//
#include <hip/hip_runtime.h>
#include <math.h>

// Shapes (fixed by the reference)
#define B_    512
#define T_    512
#define DEC_  128
#define EMB_  512
#define VOC_  30001
#define VEXT_ 30051   // VOC_ + 50 OOV

typedef float f32x4 __attribute__((ext_vector_type(4)));
typedef short s16x4 __attribute__((ext_vector_type(4)));
typedef short s16x8 __attribute__((ext_vector_type(8)));
typedef unsigned u32x4 __attribute__((ext_vector_type(4)));

#define L2E 1.4426950408889634f

// clamp-free fast sigmoid/tanh: exact at +/-inf, NaN-free for finite x
__device__ __forceinline__ float sigmoid_f(float x) {
  return __builtin_amdgcn_rcpf(1.f + exp2f(-x * L2E));
}
__device__ __forceinline__ float tanh_f(float x) {
  return 1.f - 2.f * __builtin_amdgcn_rcpf(exp2f(x * (2.f * L2E)) + 1.f);
}
// f32 -> bf16 (RNE) scalar
__device__ __forceinline__ short f2bf(float f) {
  unsigned u = __builtin_bit_cast(unsigned, f);
  u += 0x7FFFu + ((u >> 16) & 1u);
  return (short)(u >> 16);
}
__device__ __forceinline__ float bf2f(unsigned short h) {
  return __builtin_bit_cast(float, (unsigned)h << 16);
}
__device__ __forceinline__ float bitsf(unsigned u) {
  return __builtin_bit_cast(float, u);
}
// packed f32x2 -> bf16x2 in one VALU op (gfx950 v_cvt_pk_bf16_f32, RNE)
__device__ __forceinline__ unsigned pk_bf16(float lo, float hi) {
  unsigned r;
  asm("v_cvt_pk_bf16_f32 %0, %1, %2" : "=v"(r) : "v"(lo), "v"(hi));
  return r;
}
__device__ __forceinline__ s16x8 pk8(f32x4 w0, f32x4 w1) {
  u32x4 r;
  r[0] = pk_bf16(w0[0], w0[1]); r[1] = pk_bf16(w0[2], w0[3]);
  r[2] = pk_bf16(w1[0], w1[1]); r[3] = pk_bf16(w1[2], w1[3]);
  return __builtin_bit_cast(s16x8, r);
}
// 128B-aligned bf16 logits base for row b, inside row b's own d_out slot.
__device__ __forceinline__ unsigned short* logit_row(float* outF, int b) {
  size_t byteoff = ((size_t)b * VEXT_ * 4 + 127) & ~(size_t)127;
  return (unsigned short*)((char*)outF + byteoff);
}
// async global -> LDS, 16 bytes per lane (dest = wave-uniform base + lane*16)
__device__ __forceinline__ void gload_lds16(const void* g, void* l) {
  __builtin_amdgcn_global_load_lds(
      (const __attribute__((address_space(1))) void*)g,
      (__attribute__((address_space(3))) void*)l, 16, 0, 0);
}

// ---------------------------------------------------------------------------
// K0 (K=32 layout): Wh_w (128x128 f32) -> bf16 B-fragments, fragment-linear.
// ---------------------------------------------------------------------------
__global__ __launch_bounds__(256) void k0_prep32(
    const float* __restrict__ Whw, unsigned short* __restrict__ bw) {
  const int t = threadIdx.x;
#pragma unroll
  for (int i = 0; i < 8; ++i) {
    int p = t + 256 * i;          // 0..2047 (frag, lane)
    int f = p >> 6, l = p & 63;
    int nf = f >> 2, kf = f & 3;
    int row = nf * 16 + (l & 15);
    int col = kf * 32 + (l >> 4) * 8;
    const float* src = Whw + row * 128 + col;
    f32x4 w0 = *(const f32x4*)src;
    f32x4 w1 = *(const f32x4*)(src + 4);
    *(s16x8*)&bw[p * 8] = pk8(w0, w1);
  }
}

// ---------------------------------------------------------------------------
// K0b: V2_w (30001x384 f32) -> bf16 ROW-MAJOR [30080][384], rows >= VOC_ = 0.
// ---------------------------------------------------------------------------
__global__ __launch_bounds__(256) void k0b_prepv2h(
    const float* __restrict__ V2w, unsigned short* __restrict__ v2bh) {
  int p = blockIdx.x * 256 + threadIdx.x;   // chunk index, 48 chunks per row
  int row = p / 48;
  int k = (p - row * 48) * 8;
  s16x8 bb;
  if (row < VOC_) {
    const float* src = V2w + (size_t)row * 384 + k;
    f32x4 w0 = *(const f32x4*)src;
    f32x4 w1 = *(const f32x4*)(src + 4);
    bb = pk8(w0, w1);
  } else {
    bb = (s16x8){0, 0, 0, 0, 0, 0, 0, 0};
  }
  *(s16x8*)&v2bh[(size_t)p * 8] = bb;
}

// ---------------------------------------------------------------------------
// K0c: V1_w (384x256 f32) -> bf16 row-major [384][256]. grid = 48 x 256.
// ---------------------------------------------------------------------------
__global__ __launch_bounds__(256) void k0c_prepv1(
    const float* __restrict__ V1w, unsigned short* __restrict__ v1bh) {
  int p = blockIdx.x * 256 + threadIdx.x;   // 12288 threads, 8 elems each
  int row = p >> 5, k = (p & 31) * 8;
  const float* src = V1w + row * 256 + k;
  *(s16x8*)&v1bh[p * 8] = pk8(*(const f32x4*)src, *(const f32x4*)(src + 4));
}

// ---------------------------------------------------------------------------
// K1: x1[b,f] = sum_k [emb[x[b]] | ctx_prev][b,k] * W1_w[f,k] + W1_b[f]
// ---------------------------------------------------------------------------
__global__ __launch_bounds__(256) void k1_x1(
    const float* __restrict__ emb, const int* __restrict__ x,
    const float* __restrict__ ctxp, const float* __restrict__ W1w,
    const float* __restrict__ W1b, float* __restrict__ x1) {
  __shared__ float As[32][33];
  __shared__ float Ws[32][33];
  const int tid = threadIdx.x;
  const int f0 = blockIdx.x * 32, b0 = blockIdx.y * 32;
  const int row = tid >> 3, seg = tid & 7;
  const int tx = tid & 15, ty = tid >> 4;
  float a00 = 0.f, a01 = 0.f, a10 = 0.f, a11 = 0.f;
  for (int k0 = 0; k0 < 640; k0 += 32) {
    int k = k0 + seg * 4;
    f32x4 av;
    if (k < 512) {
      int xb = x[b0 + row];
      av = *(const f32x4*)(emb + xb * 512 + k);
    } else {
      av = *(const f32x4*)(ctxp + (b0 + row) * 128 + (k - 512));
    }
    As[row][seg * 4 + 0] = av[0]; As[row][seg * 4 + 1] = av[1];
    As[row][seg * 4 + 2] = av[2]; As[row][seg * 4 + 3] = av[3];
    f32x4 wv = *(const f32x4*)(W1w + (f0 + row) * 640 + k);
    Ws[row][seg * 4 + 0] = wv[0]; Ws[row][seg * 4 + 1] = wv[1];
    Ws[row][seg * 4 + 2] = wv[2]; Ws[row][seg * 4 + 3] = wv[3];
    __syncthreads();
#pragma unroll
    for (int kk = 0; kk < 32; ++kk) {
      float v0 = As[ty * 2][kk], v1 = As[ty * 2 + 1][kk];
      float w0 = Ws[tx * 2][kk], w1 = Ws[tx * 2 + 1][kk];
      a00 += v0 * w0; a01 += v0 * w1; a10 += v1 * w0; a11 += v1 * w1;
    }
    __syncthreads();
  }
  int fo = f0 + tx * 2, bo = b0 + ty * 2;
  x1[bo * 512 + fo]           = a00 + W1b[fo];
  x1[bo * 512 + fo + 1]       = a01 + W1b[fo + 1];
  x1[(bo + 1) * 512 + fo]     = a10 + W1b[fo];
  x1[(bo + 1) * 512 + fo + 1] = a11 + W1b[fo + 1];
}

// ---------------------------------------------------------------------------
// K2: gates[b,j] = sum [x1 | h_prev][b,k] * [W_ih | W_hh][j,k] + b_ih + b_hh
// ---------------------------------------------------------------------------
__global__ __launch_bounds__(256) void k2_gates(
    const float* __restrict__ x1, const float* __restrict__ hprev,
    const float* __restrict__ Wih, const float* __restrict__ Whh,
    const float* __restrict__ bih, const float* __restrict__ bhh,
    float* __restrict__ gates) {
  __shared__ float As[32][33];
  __shared__ float Ws[32][33];
  const int tid = threadIdx.x;
  const int f0 = blockIdx.x * 32, b0 = blockIdx.y * 32;
  const int row = tid >> 3, seg = tid & 7;
  const int tx = tid & 15, ty = tid >> 4;
  float a00 = 0.f, a01 = 0.f, a10 = 0.f, a11 = 0.f;
  for (int k0 = 0; k0 < 640; k0 += 32) {
    int k = k0 + seg * 4;
    f32x4 av, wv;
    if (k < 512) {
      av = *(const f32x4*)(x1 + (b0 + row) * 512 + k);
      wv = *(const f32x4*)(Wih + (f0 + row) * 512 + k);
    } else {
      av = *(const f32x4*)(hprev + (b0 + row) * 128 + (k - 512));
      wv = *(const f32x4*)(Whh + (f0 + row) * 128 + (k - 512));
    }
    As[row][seg * 4 + 0] = av[0]; As[row][seg * 4 + 1] = av[1];
    As[row][seg * 4 + 2] = av[2]; As[row][seg * 4 + 3] = av[3];
    Ws[row][seg * 4 + 0] = wv[0]; Ws[row][seg * 4 + 1] = wv[1];
    Ws[row][seg * 4 + 2] = wv[2]; Ws[row][seg * 4 + 3] = wv[3];
    __syncthreads();
#pragma unroll
    for (int kk = 0; kk < 32; ++kk) {
      float v0 = As[ty * 2][kk], v1 = As[ty * 2 + 1][kk];
      float w0 = Ws[tx * 2][kk], w1 = Ws[tx * 2 + 1][kk];
      a00 += v0 * w0; a01 += v0 * w1; a10 += v1 * w0; a11 += v1 * w1;
    }
    __syncthreads();
  }
  int fo = f0 + tx * 2, bo = b0 + ty * 2;
  gates[bo * 512 + fo]           = a00 + bih[fo] + bhh[fo];
  gates[bo * 512 + fo + 1]       = a01 + bih[fo + 1] + bhh[fo + 1];
  gates[(bo + 1) * 512 + fo]     = a10 + bih[fo] + bhh[fo];
  gates[(bo + 1) * 512 + fo + 1] = a11 + bih[fo + 1] + bhh[fo + 1];
}

// ---------------------------------------------------------------------------
// K3: LSTM cell + dec_f; also writes h (bf16) into hc_bf[b][0..127].
// ---------------------------------------------------------------------------
__global__ __launch_bounds__(128) void k3_lstm(
    const float* __restrict__ gates, const float* __restrict__ cprev,
    const float* __restrict__ Wsw, const float* __restrict__ Wsb,
    float* __restrict__ out_h, float* __restrict__ out_c,
    float* __restrict__ decf, unsigned short* __restrict__ hc_bf) {
  __shared__ float st[256];
  int b = blockIdx.x, d = threadIdx.x;
  const float* g = gates + b * 512;
  float iv = sigmoid_f(g[d]);
  float fv = sigmoid_f(g[128 + d]);
  float gv = tanh_f(g[256 + d]);
  float ov = sigmoid_f(g[384 + d]);
  float c = fv * cprev[b * 128 + d] + iv * gv;
  float h = ov * tanh_f(c);
  out_h[b * 128 + d] = h;
  out_c[b * 128 + d] = c;
  hc_bf[b * 256 + d] = (unsigned short)f2bf(h);
  st[d] = h; st[128 + d] = c;
  __syncthreads();
  float acc = Wsb[d];
  const float* wr = Wsw + d * 256;
#pragma unroll 4
  for (int k = 0; k < 256; ++k) acc += st[k] * wr[k];
  decf[b * 128 + d] = acc;
}

// ---------------------------------------------------------------------------
// K45 v5 (SPLIT-T): grid = 1024 blocks (b = bx>>1, half g = bx&1); each
// block covers 256 t-rows of one b (8 waves x 32 t). E1-shift makes softmax
// sums ADDITIVE across blocks -> block writes partial S (Sp), partial
// unnormalized ctx (cxp), and unnormalized w (wbuf). Merge happens in
// k6b_merge. 2x blocks/CU vs R13 -> 2x independent h_i load streams per CU
// (the R11/R12-diagnosed latency-parallelism limit).
// ---------------------------------------------------------------------------
__global__ __launch_bounds__(512) void k45_attn(
    const float* __restrict__ h_i, const unsigned short* __restrict__ bw,
    const float* __restrict__ decf, const float* __restrict__ cov,
    const float* __restrict__ Wcw, const float* __restrict__ Vw,
    float* __restrict__ wbuf, float* __restrict__ cxp,
    float* __restrict__ Sp) {
  __shared__ unsigned short whl[16384];   // 32 KB frag-linear Wh
  __shared__ float sm[256];
  __shared__ float red[8][128];
  __shared__ float wred[8];
  __shared__ float dls[128], vls[128], wls[128];
  const int bx = blockIdx.x;
  const int b = bx >> 1, g = bx & 1;
  const int tid = threadIdx.x;
  const int wv = tid >> 6, lane = tid & 63;
  const int lm = lane & 15, lg = lane >> 4;
  const int t0w = g * 256 + wv * 32;      // global t base for this wave

#pragma unroll
  for (int i = 0; i < 4; ++i)
    gload_lds16(&bw[(tid + i * 512) * 8], &whl[(tid + i * 512) * 8]);
  if (tid < 128) {
    dls[tid] = decf[b * 128 + tid];
    vls[tid] = Vw[tid];
    wls[tid] = Wcw[tid];
  }
  __syncthreads();   // drains vmcnt incl. global_load_lds

  // E1 = ||Vw||_1 : bit-identical on every lane/wave/block
  const volatile float* vlp = vls;
  const volatile float* dlp = dls;
  const volatile float* wlp = wls;
  float E1 = 0.f;
#pragma unroll
  for (int nf = 0; nf < 8; ++nf) E1 += fabsf(vlp[nf * 16 + lm]);
  E1 += __shfl_xor(E1, 1); E1 += __shfl_xor(E1, 2);
  E1 += __shfl_xor(E1, 4); E1 += __shfl_xor(E1, 8);

  const f32x4 zf4 = {0.f, 0.f, 0.f, 0.f};
  const float* abase = h_i + ((size_t)(b * 512 + t0w + lm)) * 128 + lg * 8;

  f32x4 r0, r1, r2, r3, r4, r5, r6, r7;   // raw chunk buffer
  f32x4 cv_raw;
  f32x4 c0 = zf4, c1 = zf4, c2 = zf4, c3 = zf4;   // ctx accumulators
  f32x4 c4 = zf4, c5 = zf4, c6 = zf4, c7 = zf4;
#define K45_LOADC(c)                                            \
  do {                                                          \
    const float* p_ = abase + (size_t)(c) * 16 * 128;           \
    r0 = *(const f32x4*)(p_ + 0);   r1 = *(const f32x4*)(p_ + 4);   \
    r2 = *(const f32x4*)(p_ + 32);  r3 = *(const f32x4*)(p_ + 36);  \
    r4 = *(const f32x4*)(p_ + 64);  r5 = *(const f32x4*)(p_ + 68);  \
    r6 = *(const f32x4*)(p_ + 96);  r7 = *(const f32x4*)(p_ + 100); \
    cv_raw = *(const f32x4*)&cov[b * 512 + t0w + (c) * 16 + lg * 4];\
  } while (0)
#define K45_ACC(ca, cb, pk)                                         \
  do {                                                              \
    u32x4 q_ = __builtin_bit_cast(u32x4, pk);                       \
    ca[0] += w * bitsf(q_[0] << 16); ca[1] += w * bitsf(q_[0] & 0xFFFF0000u); \
    ca[2] += w * bitsf(q_[1] << 16); ca[3] += w * bitsf(q_[1] & 0xFFFF0000u); \
    cb[0] += w * bitsf(q_[2] << 16); cb[1] += w * bitsf(q_[2] & 0xFFFF0000u); \
    cb[2] += w * bitsf(q_[3] << 16); cb[3] += w * bitsf(q_[3] & 0xFFFF0000u); \
  } while (0)

  K45_LOADC(0);
#pragma unroll
  for (int c = 0; c < 2; ++c) {
    s16x8 pk0 = pk8(r0, r1), pk1 = pk8(r2, r3);
    s16x8 pk2 = pk8(r4, r5), pk3 = pk8(r6, r7);
    f32x4 cov4 = cv_raw;
    if (c < 1) K45_LOADC(c + 1);  // next chunk in flight during compute

    float e4[4] = {0.f, 0.f, 0.f, 0.f};
#pragma unroll
    for (int nf = 0; nf < 8; ++nf) {
      float dv = dlp[nf * 16 + lm];
      float vw = vlp[nf * 16 + lm];
      float wc = wlp[nf * 16 + lm];
      s16x8 b0_ = *(const s16x8*)&whl[((nf * 4 + 0) * 64 + lane) * 8];
      s16x8 b1_ = *(const s16x8*)&whl[((nf * 4 + 1) * 64 + lane) * 8];
      s16x8 b2_ = *(const s16x8*)&whl[((nf * 4 + 2) * 64 + lane) * 8];
      s16x8 b3_ = *(const s16x8*)&whl[((nf * 4 + 3) * 64 + lane) * 8];
      f32x4 cc = zf4;
      cc = __builtin_amdgcn_mfma_f32_16x16x32_bf16(pk0, b0_, cc, 0, 0, 0);
      cc = __builtin_amdgcn_mfma_f32_16x16x32_bf16(pk1, b1_, cc, 0, 0, 0);
      cc = __builtin_amdgcn_mfma_f32_16x16x32_bf16(pk2, b2_, cc, 0, 0, 0);
      cc = __builtin_amdgcn_mfma_f32_16x16x32_bf16(pk3, b3_, cc, 0, 0, 0);
#pragma unroll
      for (int r = 0; r < 4; ++r) {
        float v = cc[r] + dv + cov4[r] * wc;
        e4[r] += vw * tanh_f(v);
      }
    }
    // allreduce over the 16 d-column lanes
#pragma unroll
    for (int i = 0; i < 4; ++i) {
      float v = e4[i];
      v += __shfl_xor(v, 1); v += __shfl_xor(v, 2);
      v += __shfl_xor(v, 4); v += __shfl_xor(v, 8);
      e4[i] = v;
    }
    if (lm == 0) {
#pragma unroll
      for (int r = 0; r < 4; ++r)
        sm[wv * 32 + c * 16 + lg * 4 + r] = e4[r];
    }
    // w for THIS lane's row (t = c*16 + lm)
    int src = (lm >> 2) << 4;
    float s0 = __shfl(e4[0], src), s1 = __shfl(e4[1], src);
    float s2 = __shfl(e4[2], src), s3 = __shfl(e4[3], src);
    int rr = lm & 3;
    float ev = rr == 0 ? s0 : (rr == 1 ? s1 : (rr == 2 ? s2 : s3));
    float w = exp2f((ev - E1) * L2E);
    K45_ACC(c0, c1, pk0);
    K45_ACC(c2, c3, pk1);
    K45_ACC(c4, c5, pk2);
    K45_ACC(c6, c7, pk3);
  }
#undef K45_LOADC
#undef K45_ACC

  // reduce ctx over the 16 rows held across lm lanes
#define BFLY(x) { x += __shfl_xor(x, 1); x += __shfl_xor(x, 2); \
                  x += __shfl_xor(x, 4); x += __shfl_xor(x, 8); }
#pragma unroll
  for (int j = 0; j < 4; ++j) {
    BFLY(c0[j]); BFLY(c1[j]); BFLY(c2[j]); BFLY(c3[j]);
    BFLY(c4[j]); BFLY(c5[j]); BFLY(c6[j]); BFLY(c7[j]);
  }
#undef BFLY
  if (lm == 0) {
    float* rw = &red[wv][lg * 8];
#pragma unroll
    for (int j = 0; j < 4; ++j) {
      rw[j] = c0[j];       rw[4 + j] = c1[j];
      rw[32 + j] = c2[j];  rw[36 + j] = c3[j];
      rw[64 + j] = c4[j];  rw[68 + j] = c5[j];
      rw[96 + j] = c6[j];  rw[100 + j] = c7[j];
    }
  }
  __syncthreads();

  // partial ctx (UNNORMALIZED) for this half
  if (tid < 128) {
    float sa = 0.f;
#pragma unroll
    for (int q = 0; q < 8; ++q) sa += red[q][tid];
    cxp[(size_t)bx * 128 + tid] = sa;
  }
  // unnormalized w + partial sum for this half (256 t, threads 0..255)
  if (tid < 256) {
    float e = sm[tid];
    float w2 = exp2f((e - E1) * L2E);
    wbuf[b * 512 + g * 256 + tid] = w2;
    float s = w2;
    for (int off = 32; off; off >>= 1) s += __shfl_xor(s, off);
    if (lane == 0) wred[wv] = s;
  }
  __syncthreads();
  if (tid == 0) Sp[bx] = wred[0] + wred[1] + wred[2] + wred[3];
}

// ---------------------------------------------------------------------------
// K6b_merge: combine split halves (S = Sp0+Sp1; ctx = (cxp0+cxp1)*rS), then
// p_gen, cov_out, attn_dist, hc_bf-ctx. One block (256 thr) per b.
// ---------------------------------------------------------------------------
__global__ __launch_bounds__(256) void k6b_merge(
    const float* __restrict__ out_h, const float* __restrict__ out_c,
    const float* __restrict__ emb, const int* __restrict__ x,
    const float* __restrict__ W2w, const float* __restrict__ W2b,
    const float* __restrict__ cov, const float* __restrict__ wbuf,
    const float* __restrict__ cxp, const float* __restrict__ Sp,
    float* __restrict__ pgen, float* __restrict__ attn_out,
    float* __restrict__ cov_out, float* __restrict__ ctx_out,
    unsigned short* __restrict__ hc_bf) {
  __shared__ float cat[896];  // [ctx(128) | h(128) | c(128) | xe(512)]
  __shared__ float wr_[4];
  int b = blockIdx.x, tid = threadIdx.x;
  float rS = __builtin_amdgcn_rcpf(Sp[2 * b] + Sp[2 * b + 1]);
  if (tid < 128) {
    float cx = (cxp[(size_t)(2 * b) * 128 + tid] +
                cxp[(size_t)(2 * b + 1) * 128 + tid]) * rS;
    ctx_out[b * 128 + tid] = cx;
    hc_bf[b * 256 + 128 + tid] = (unsigned short)f2bf(cx);
    cat[tid] = cx;
    cat[128 + tid] = out_h[b * 128 + tid];
  } else {
    int q = tid - 128;
    cat[256 + q] = out_c[b * 128 + q];
  }
  int xb = x[b];
  for (int k = tid; k < 512; k += 256) cat[384 + k] = emb[xb * 512 + k];
  __syncthreads();
  float p = 0.f;
  for (int k = tid; k < 896; k += 256) p += cat[k] * W2w[k];
  for (int off = 32; off; off >>= 1) p += __shfl_xor(p, off);
  if ((tid & 63) == 0) wr_[tid >> 6] = p;
  __syncthreads();
  float pg = sigmoid_f(wr_[0] + wr_[1] + wr_[2] + wr_[3] + W2b[0]);
  if (tid == 0) pgen[b] = pg;
  float om = 1.f - pg;
  float w0 = wbuf[b * 512 + tid], w1 = wbuf[b * 512 + 256 + tid];
  float a0 = w0 * rS, a1 = w1 * rS;
  cov_out[b * 512 + tid]       = cov[b * 512 + tid] + a0;
  cov_out[b * 512 + 256 + tid] = cov[b * 512 + 256 + tid] + a1;
  attn_out[b * 512 + tid]       = om * a0;
  attn_out[b * 512 + 256 + tid] = om * a1;
}

// ---------------------------------------------------------------------------
// K6a: pv1(bf16) = hc_bf @ v1bh^T + V1_b  (M=512, N=384, K=256).
// ---------------------------------------------------------------------------
__global__ __launch_bounds__(256) void k6a_pv1(
    const unsigned short* __restrict__ hc_bf, const unsigned short* __restrict__ v1bh,
    const float* __restrict__ V1b, unsigned short* __restrict__ pv1bf) {
  __shared__ char smem[33280];
  unsigned short* Al = (unsigned short*)smem;
  unsigned short* Bl = (unsigned short*)(smem + 16384);
  const int bx = blockIdx.x;
  const int rp = bx & 3, cp = bx >> 2;     // cp 0..2
  const int r0 = rp * 128, c0 = cp * 128;
  const int tid = threadIdx.x;
  const int wv = tid >> 6, lane = tid & 63;
  const int lm = lane & 15, lg = lane >> 4;
  const int rh2 = wv >> 1, ch = wv & 1;

  const f32x4 zf4 = {0.f, 0.f, 0.f, 0.f};
  f32x4 acc[4][4];
#pragma unroll
  for (int m = 0; m < 4; ++m)
#pragma unroll
    for (int nf = 0; nf < 4; ++nf) acc[m][nf] = zf4;

  for (int ks = 0; ks < 4; ++ks) {
#pragma unroll
    for (int i = 0; i < 4; ++i) {
      int fi = wv * 4 + i;
      int rt = fi >> 1, kf = fi & 1;
      const unsigned short* sa =
          hc_bf + (r0 + rt * 16 + lm) * 256 + ks * 64 + kf * 32 + lg * 8;
      gload_lds16(sa, &Al[fi * 512 + lane * 8]);
      const unsigned short* sb =
          v1bh + (c0 + rt * 16 + lm) * 256 + ks * 64 + kf * 32 + lg * 8;
      gload_lds16(sb, &Bl[fi * 512 + lane * 8]);
    }
    __syncthreads();
#pragma unroll
    for (int kf = 0; kf < 2; ++kf) {
      s16x8 a[4];
#pragma unroll
      for (int m = 0; m < 4; ++m)
        a[m] = *(const s16x8*)&Al[(((rh2 * 4 + m) * 2) + kf) * 512 + lane * 8];
#pragma unroll
      for (int nf = 0; nf < 4; ++nf) {
        s16x8 bfr = *(const s16x8*)&Bl[(((ch * 4 + nf) * 2) + kf) * 512 + lane * 8];
#pragma unroll
        for (int m = 0; m < 4; ++m)
          acc[m][nf] = __builtin_amdgcn_mfma_f32_16x16x32_bf16(a[m], bfr, acc[m][nf], 0, 0, 0);
      }
    }
    __syncthreads();
  }

  const int cw0 = c0 + ch * 64;
  float bias[4];
#pragma unroll
  for (int nf = 0; nf < 4; ++nf)
    bias[nf] = V1b[cw0 + nf * 16 + lm];

  float* T = (float*)smem + wv * 2080;
  const int rq = lane >> 4, cq = lane & 15;
#pragma unroll
  for (int p = 0; p < 2; ++p) {
#pragma unroll
    for (int mm = 0; mm < 2; ++mm) {
      int m = p * 2 + mm;
#pragma unroll
      for (int nf = 0; nf < 4; ++nf)
#pragma unroll
        for (int r = 0; r < 4; ++r)
          T[(mm * 16 + lg * 4 + r) * 65 + nf * 16 + lm] = acc[m][nf][r] + bias[nf];
    }
#pragma unroll
    for (int it = 0; it < 8; ++it) {
      int trow = it * 4 + rq;
      f32x4 vv = *(const f32x4*)&T[trow * 65 + cq * 4];
      s16x4 hb;
      hb[0] = f2bf(vv[0]); hb[1] = f2bf(vv[1]); hb[2] = f2bf(vv[2]); hb[3] = f2bf(vv[3]);
      int orow = r0 + rh2 * 64 + p * 32 + trow;
      *(s16x4*)&pv1bf[orow * 384 + cw0 + cq * 4] = hb;
    }
  }
}

// ---------------------------------------------------------------------------
// K7 v6 (m97-structure): logits(bf16) = pv1 @ v2bh^T + V2b -> aligned region
// in each d_out row slot. 940 blocks, 128x128 tile, BK=64, 4 waves.
// ---------------------------------------------------------------------------
__global__ __launch_bounds__(256) void k7_vocab(
    const unsigned short* __restrict__ pv1bf, const unsigned short* __restrict__ v2bh,
    const float* __restrict__ V2b, float* __restrict__ outF) {
  __shared__ char smem[33280];
  unsigned short* Al = (unsigned short*)smem;
  unsigned short* Bl = (unsigned short*)(smem + 16384);
  const int bx = blockIdx.x;
  const int rp = bx & 3, cp = bx >> 2;
  const int r0 = rp * 128, c0 = cp * 128;
  const int tid = threadIdx.x;
  const int wv = tid >> 6, lane = tid & 63;
  const int lm = lane & 15, lg = lane >> 4;
  const int rh2 = wv >> 1, ch = wv & 1;

  const f32x4 zf4 = {0.f, 0.f, 0.f, 0.f};
  f32x4 acc[4][4];
#pragma unroll
  for (int m = 0; m < 4; ++m)
#pragma unroll
    for (int nf = 0; nf < 4; ++nf) acc[m][nf] = zf4;

  for (int ks = 0; ks < 6; ++ks) {
#pragma unroll
    for (int i = 0; i < 4; ++i) {
      int fi = wv * 4 + i;
      int rt = fi >> 1, kf = fi & 1;
      const unsigned short* sa =
          pv1bf + (r0 + rt * 16 + lm) * 384 + ks * 64 + kf * 32 + lg * 8;
      gload_lds16(sa, &Al[fi * 512 + lane * 8]);
      const unsigned short* sb =
          v2bh + (size_t)(c0 + rt * 16 + lm) * 384 + ks * 64 + kf * 32 + lg * 8;
      gload_lds16(sb, &Bl[fi * 512 + lane * 8]);
    }
    __syncthreads();
#pragma unroll
    for (int kf = 0; kf < 2; ++kf) {
      s16x8 a[4];
#pragma unroll
      for (int m = 0; m < 4; ++m)
        a[m] = *(const s16x8*)&Al[(((rh2 * 4 + m) * 2) + kf) * 512 + lane * 8];
#pragma unroll
      for (int nf = 0; nf < 4; ++nf) {
        s16x8 bfr = *(const s16x8*)&Bl[(((ch * 4 + nf) * 2) + kf) * 512 + lane * 8];
#pragma unroll
        for (int m = 0; m < 4; ++m)
          acc[m][nf] = __builtin_amdgcn_mfma_f32_16x16x32_bf16(a[m], bfr, acc[m][nf], 0, 0, 0);
      }
    }
    __syncthreads();
  }

  const int cw0 = c0 + ch * 64;
  float bias[4];
#pragma unroll
  for (int nf = 0; nf < 4; ++nf) {
    int col = cw0 + nf * 16 + lm;
    bias[nf] = (col < VOC_) ? V2b[col] : 0.f;
  }

  float* T = (float*)smem + wv * 2080;
  const int rq = lane >> 4, cq = lane & 15;
#pragma unroll
  for (int p = 0; p < 2; ++p) {
#pragma unroll
    for (int mm = 0; mm < 2; ++mm) {
      int m = p * 2 + mm;
#pragma unroll
      for (int nf = 0; nf < 4; ++nf)
#pragma unroll
        for (int r = 0; r < 4; ++r)
          T[(mm * 16 + lg * 4 + r) * 65 + nf * 16 + lm] = acc[m][nf][r] + bias[nf];
    }
#pragma unroll
    for (int it = 0; it < 8; ++it) {
      int trow = it * 4 + rq;
      f32x4 vv = *(const f32x4*)&T[trow * 65 + cq * 4];
      s16x4 hb;
      hb[0] = f2bf(vv[0]); hb[1] = f2bf(vv[1]); hb[2] = f2bf(vv[2]); hb[3] = f2bf(vv[3]);
      int orow = r0 + rh2 * 64 + p * 32 + trow;
      unsigned short* dst = logit_row(outF, orow);
      *(s16x4*)&dst[cw0 + cq * 4] = hb;
    }
  }
}

// ---------------------------------------------------------------------------
// K7 fallback (R7 kernel, proven) -- used only if ws can't hold v2bh.
// ---------------------------------------------------------------------------
__global__ __launch_bounds__(256) void k7_vocab_fb(
    const unsigned short* __restrict__ pv1bf, const float* __restrict__ V2w,
    const float* __restrict__ V2b, float* __restrict__ outF) {
  __shared__ float lt[4][32 * 65];
  const int q = blockIdx.x;
  const int nb = ((q >> 4) << 3) + (q & 7);
  const int rh = (q >> 3) & 1;
  if (nb >= 469) return;
  const int v0 = nb * 64;
  const int tid = threadIdx.x;
  const int wv = tid >> 6, lane = tid & 63;
  const int lm = lane & 15, lg = lane >> 4;
  const int r0 = rh * 256 + wv * 64;

  const f32x4 zf4 = {0.f, 0.f, 0.f, 0.f};
  f32x4 acc[4][4];
#pragma unroll
  for (int m = 0; m < 4; ++m)
#pragma unroll
    for (int nf = 0; nf < 4; ++nf) acc[m][nf] = zf4;

  int vrow[4]; bool vok[4];
#pragma unroll
  for (int nf = 0; nf < 4; ++nf) {
    int v = v0 + nf * 16 + lm;
    vok[nf] = (v < VOC_);
    vrow[nf] = vok[nf] ? v : (VOC_ - 1);
  }

#pragma unroll
  for (int kf = 0; kf < 12; ++kf) {
    s16x8 afr[4];
#pragma unroll
    for (int m = 0; m < 4; ++m)
      afr[m] = *(const s16x8*)&pv1bf[(r0 + m * 16 + lm) * 384 + kf * 32 + lg * 8];
    s16x8 bfr[4];
#pragma unroll
    for (int nf = 0; nf < 4; ++nf) {
      const float* p = V2w + (size_t)vrow[nf] * 384 + kf * 32 + lg * 8;
      f32x4 w0 = *(const f32x4*)p;
      f32x4 w1 = *(const f32x4*)(p + 4);
      if (!vok[nf]) { w0 = zf4; w1 = zf4; }
      bfr[nf] = pk8(w0, w1);
    }
#pragma unroll
    for (int m = 0; m < 4; ++m)
#pragma unroll
      for (int nf = 0; nf < 4; ++nf)
        acc[m][nf] = __builtin_amdgcn_mfma_f32_16x16x32_bf16(afr[m], bfr[nf], acc[m][nf], 0, 0, 0);
  }

  float bias[4];
#pragma unroll
  for (int nf = 0; nf < 4; ++nf)
    bias[nf] = vok[nf] ? V2b[v0 + nf * 16 + lm] : 0.f;

  float* T = lt[wv];
  const int rq = lane >> 4, cq = lane & 15;
#pragma unroll
  for (int p = 0; p < 2; ++p) {
#pragma unroll
    for (int mm = 0; mm < 2; ++mm) {
      int m = p * 2 + mm;
#pragma unroll
      for (int nf = 0; nf < 4; ++nf)
#pragma unroll
        for (int r = 0; r < 4; ++r)
          T[(mm * 16 + lg * 4 + r) * 65 + nf * 16 + lm] = acc[m][nf][r] + bias[nf];
    }
#pragma unroll
    for (int it = 0; it < 8; ++it) {
      int trow = it * 4 + rq;
      f32x4 vv = *(const f32x4*)&T[trow * 65 + cq * 4];
      s16x4 hb;
      hb[0] = f2bf(vv[0]); hb[1] = f2bf(vv[1]); hb[2] = f2bf(vv[2]); hb[3] = f2bf(vv[3]);
      int orow = r0 + p * 32 + trow;
      unsigned short* dst = logit_row(outF, orow);
      *(s16x4*)&dst[v0 + cq * 4] = hb;
    }
  }
}

// ---------------------------------------------------------------------------
// K8: per-row softmax over bf16 logits, scale by p_gen, write f32 final_dist
// in place, zero 50 OOV cols, scatter-add attn_dist (workgroup atomics).
// ---------------------------------------------------------------------------
#define K8_IT 30  // ceil(VOC_/1024)

__global__ __launch_bounds__(1024) void k8_final(
    const float* __restrict__ pgen, const int* __restrict__ code_ext,
    const float* __restrict__ attn, float* __restrict__ outF) {
  __shared__ float lm_[16], ls_[16];
  const int b = blockIdx.x, tid = threadIdx.x;
  float* row = outF + (size_t)b * VEXT_;
  const unsigned short* lrow = logit_row(outF, b);

  float lv[K8_IT];
#pragma unroll
  for (int i = 0; i < K8_IT; ++i) {
    int v = tid + i * 1024;
    lv[i] = (v < VOC_) ? bf2f(lrow[v]) : -3.4e38f;
  }
  float m = lv[0];
#pragma unroll
  for (int i = 1; i < K8_IT; ++i) m = fmaxf(m, lv[i]);
  for (int off = 32; off; off >>= 1) m = fmaxf(m, __shfl_xor(m, off));
  if ((tid & 63) == 0) lm_[tid >> 6] = m;
  __syncthreads();
  float M = lm_[0];
#pragma unroll
  for (int i = 1; i < 16; ++i) M = fmaxf(M, lm_[i]);
  float s = 0.f;
#pragma unroll
  for (int i = 0; i < K8_IT; ++i) {
    lv[i] = exp2f((lv[i] - M) * L2E);
    s += lv[i];
  }
  for (int off = 32; off; off >>= 1) s += __shfl_xor(s, off);
  if ((tid & 63) == 0) ls_[tid >> 6] = s;
  __syncthreads();
  float S = 0.f;
#pragma unroll
  for (int i = 0; i < 16; ++i) S += ls_[i];
  float pm = pgen[b] / S;
#pragma unroll
  for (int i = 0; i < K8_IT; ++i) {
    int v = tid + i * 1024;
    if (v < VOC_) row[v] = pm * lv[i];
  }
  if (tid < 50) row[VOC_ + tid] = 0.f;
  __syncthreads();  // drains vmcnt: all row stores are at the local L2
  if (tid < 512) {
    int idx = code_ext[b * 512 + tid];
    __hip_atomic_fetch_add(&row[idx], attn[b * 512 + tid],
                           __ATOMIC_RELAXED, __HIP_MEMORY_SCOPE_WORKGROUP);
  }
}

// ---------------------------------------------------------------------------
extern "C" void kernel_launch(void* const* d_in, const int* in_sizes, int n_in,
                              void* d_out, int out_size, void* d_ws, size_t ws_size,
                              hipStream_t stream) {
  (void)in_sizes; (void)n_in; (void)out_size;
  const float* h_i    = (const float*)d_in[0];
  const float* h_prev = (const float*)d_in[1];
  const float* c_prev = (const float*)d_in[2];
  const float* ctxp   = (const float*)d_in[3];
  const float* cov    = (const float*)d_in[4];
  const float* emb    = (const float*)d_in[5];
  const float* Wih    = (const float*)d_in[6];
  const float* Whh    = (const float*)d_in[7];
  const float* bih    = (const float*)d_in[8];
  const float* bhh    = (const float*)d_in[9];
  const float* W1w    = (const float*)d_in[10];
  const float* W1b    = (const float*)d_in[11];
  const float* W2w    = (const float*)d_in[12];
  const float* W2b    = (const float*)d_in[13];
  const float* V1w    = (const float*)d_in[14];
  const float* V1b    = (const float*)d_in[15];
  const float* V2w    = (const float*)d_in[16];
  const float* V2b    = (const float*)d_in[17];
  const float* Whw    = (const float*)d_in[18];
  const float* Wsw    = (const float*)d_in[19];
  const float* Wsb    = (const float*)d_in[20];
  const float* Wcw    = (const float*)d_in[21];
  const float* Vw     = (const float*)d_in[22];
  const int*   x      = (const int*)d_in[23];
  const int*   code   = (const int*)d_in[24];

  float* ws    = (float*)d_ws;
  float* x1    = ws;                 // 262144 fl; dead after k2 ->
  float* cxp   = ws;                 //   cxp (1024*128 = 131072 fl) aliases it
  float* Sp    = ws + 131072;        //   Sp (1024 fl) aliases it
  float* gates = ws + 262144;        // 262144
  float* decf  = ws + 524288;        // 65536
  unsigned short* bw = (unsigned short*)(ws + 589824);     // 16384 shorts
  unsigned short* hc_bf = (unsigned short*)(ws + 598016);  // 131072 shorts
  unsigned short* v1bh  = (unsigned short*)(ws + 663552);  // 98304 shorts
  float* wbuf  = ws + 851968;        // 262144 (unnormalized softmax weights)
  unsigned short* pv1bf = (unsigned short*)(ws + 1114112); // 196608 shorts
  float* pgen  = ws + 1212416;       // 512
  unsigned short* v2bh = (unsigned short*)(ws + 1212928);  // 11,550,720 shorts
  const size_t WS_NEEDED = (size_t)(1212928 + 5775360) * 4;
  const bool use_v6 = (ws_size >= WS_NEEDED);

  float* outF  = (float*)d_out;                    // final_dist 512 x 30051
  float* attn  = outF + (size_t)512 * VEXT_;       // 262144
  float* o_h   = attn + 262144;                    // 65536
  float* o_c   = o_h + 65536;                      // 65536
  float* o_cov = o_c + 65536;                      // 262144
  float* o_ctx = o_cov + 262144;                   // 65536

  k0_prep32<<<1, 256, 0, stream>>>(Whw, bw);
  if (use_v6) k0b_prepv2h<<<5640, 256, 0, stream>>>(V2w, v2bh);
  k0c_prepv1<<<48, 256, 0, stream>>>(V1w, v1bh);
  k1_x1<<<dim3(16, 16), 256, 0, stream>>>(emb, x, ctxp, W1w, W1b, x1);
  k2_gates<<<dim3(16, 16), 256, 0, stream>>>(x1, h_prev, Wih, Whh, bih, bhh, gates);
  k3_lstm<<<512, 128, 0, stream>>>(gates, c_prev, Wsw, Wsb, o_h, o_c, decf, hc_bf);
  k45_attn<<<1024, 512, 0, stream>>>(h_i, bw, decf, cov, Wcw, Vw, wbuf, cxp, Sp);
  k6b_merge<<<512, 256, 0, stream>>>(o_h, o_c, emb, x, W2w, W2b, cov, wbuf,
                                     cxp, Sp, pgen, attn, o_cov, o_ctx, hc_bf);
  k6a_pv1<<<12, 256, 0, stream>>>(hc_bf, v1bh, V1b, pv1bf);
  if (use_v6)
    k7_vocab<<<940, 256, 0, stream>>>(pv1bf, v2bh, V2b, outF);
  else
    k7_vocab_fb<<<944, 256, 0, stream>>>(pv1bf, V2w, V2b, outF);
  k8_final<<<512, 1024, 0, stream>>>(pgen, code, attn, outF);
}

// Round 16
// 211.259 us; speedup vs baseline: 1.1168x; 1.1168x over previous
//
#include <hip/hip_runtime.h>
#include <math.h>

// Shapes (fixed by the reference)
#define B_    512
#define T_    512
#define DEC_  128
#define EMB_  512
#define VOC_  30001
#define VEXT_ 30051   // VOC_ + 50 OOV

typedef float f32x4 __attribute__((ext_vector_type(4)));
typedef short s16x4 __attribute__((ext_vector_type(4)));
typedef short s16x8 __attribute__((ext_vector_type(8)));
typedef unsigned u32x4 __attribute__((ext_vector_type(4)));

#define L2E 1.4426950408889634f

// clamp-free fast sigmoid/tanh: exact at +/-inf, NaN-free for finite x
__device__ __forceinline__ float sigmoid_f(float x) {
  return __builtin_amdgcn_rcpf(1.f + exp2f(-x * L2E));
}
__device__ __forceinline__ float tanh_f(float x) {
  return 1.f - 2.f * __builtin_amdgcn_rcpf(exp2f(x * (2.f * L2E)) + 1.f);
}
// f32 -> bf16 (RNE) scalar
__device__ __forceinline__ short f2bf(float f) {
  unsigned u = __builtin_bit_cast(unsigned, f);
  u += 0x7FFFu + ((u >> 16) & 1u);
  return (short)(u >> 16);
}
__device__ __forceinline__ float bf2f(unsigned short h) {
  return __builtin_bit_cast(float, (unsigned)h << 16);
}
__device__ __forceinline__ float bitsf(unsigned u) {
  return __builtin_bit_cast(float, u);
}
// packed f32x2 -> bf16x2 in one VALU op (gfx950 v_cvt_pk_bf16_f32, RNE)
__device__ __forceinline__ unsigned pk_bf16(float lo, float hi) {
  unsigned r;
  asm("v_cvt_pk_bf16_f32 %0, %1, %2" : "=v"(r) : "v"(lo), "v"(hi));
  return r;
}
__device__ __forceinline__ s16x8 pk8(f32x4 w0, f32x4 w1) {
  u32x4 r;
  r[0] = pk_bf16(w0[0], w0[1]); r[1] = pk_bf16(w0[2], w0[3]);
  r[2] = pk_bf16(w1[0], w1[1]); r[3] = pk_bf16(w1[2], w1[3]);
  return __builtin_bit_cast(s16x8, r);
}
// 128B-aligned bf16 logits base for row b, inside row b's own d_out slot.
__device__ __forceinline__ unsigned short* logit_row(float* outF, int b) {
  size_t byteoff = ((size_t)b * VEXT_ * 4 + 127) & ~(size_t)127;
  return (unsigned short*)((char*)outF + byteoff);
}
// async global -> LDS, 16 bytes per lane (dest = wave-uniform base + lane*16)
__device__ __forceinline__ void gload_lds16(const void* g, void* l) {
  __builtin_amdgcn_global_load_lds(
      (const __attribute__((address_space(1))) void*)g,
      (__attribute__((address_space(3))) void*)l, 16, 0, 0);
}

// ---------------------------------------------------------------------------
// K0 (K=32 layout): Wh_w (128x128 f32) -> bf16 B-fragments, fragment-linear.
// ---------------------------------------------------------------------------
__global__ __launch_bounds__(256) void k0_prep32(
    const float* __restrict__ Whw, unsigned short* __restrict__ bw) {
  const int t = threadIdx.x;
#pragma unroll
  for (int i = 0; i < 8; ++i) {
    int p = t + 256 * i;          // 0..2047 (frag, lane)
    int f = p >> 6, l = p & 63;
    int nf = f >> 2, kf = f & 3;
    int row = nf * 16 + (l & 15);
    int col = kf * 32 + (l >> 4) * 8;
    const float* src = Whw + row * 128 + col;
    f32x4 w0 = *(const f32x4*)src;
    f32x4 w1 = *(const f32x4*)(src + 4);
    *(s16x8*)&bw[p * 8] = pk8(w0, w1);
  }
}

// ---------------------------------------------------------------------------
// K0b: V2_w (30001x384 f32) -> bf16 ROW-MAJOR [30080][384], rows >= VOC_ = 0.
// ---------------------------------------------------------------------------
__global__ __launch_bounds__(256) void k0b_prepv2h(
    const float* __restrict__ V2w, unsigned short* __restrict__ v2bh) {
  int p = blockIdx.x * 256 + threadIdx.x;   // chunk index, 48 chunks per row
  int row = p / 48;
  int k = (p - row * 48) * 8;
  s16x8 bb;
  if (row < VOC_) {
    const float* src = V2w + (size_t)row * 384 + k;
    f32x4 w0 = *(const f32x4*)src;
    f32x4 w1 = *(const f32x4*)(src + 4);
    bb = pk8(w0, w1);
  } else {
    bb = (s16x8){0, 0, 0, 0, 0, 0, 0, 0};
  }
  *(s16x8*)&v2bh[(size_t)p * 8] = bb;
}

// ---------------------------------------------------------------------------
// K0c: V1_w (384x256 f32) -> bf16 row-major [384][256]. grid = 48 x 256.
// ---------------------------------------------------------------------------
__global__ __launch_bounds__(256) void k0c_prepv1(
    const float* __restrict__ V1w, unsigned short* __restrict__ v1bh) {
  int p = blockIdx.x * 256 + threadIdx.x;   // 12288 threads, 8 elems each
  int row = p >> 5, k = (p & 31) * 8;
  const float* src = V1w + row * 256 + k;
  *(s16x8*)&v1bh[p * 8] = pk8(*(const f32x4*)src, *(const f32x4*)(src + 4));
}

// ---------------------------------------------------------------------------
// K0d: prep bf16 operands for the k1/k2 MFMA GEMMs (R16):
//  abuf  [512][640] = [emb[x[b]] | ctx_prev]        (A of k1)
//  a2buf [512][640] cols 512..639 = h_prev          (A of k2; cols 0..511
//                                                    filled by k1mm = x1)
//  w1b   [512][640] = W1_w                          (B of k1)
//  w2b   [512][640] = [W_ih | W_hh]                 (B of k2)
// grid = 512 x 256 (131072 8-elem groups).
// ---------------------------------------------------------------------------
__global__ __launch_bounds__(256) void k0d_prep12(
    const float* __restrict__ emb, const int* __restrict__ x,
    const float* __restrict__ ctxp, const float* __restrict__ hprev,
    const float* __restrict__ W1w, const float* __restrict__ Wih,
    const float* __restrict__ Whh,
    unsigned short* __restrict__ abuf, unsigned short* __restrict__ a2buf,
    unsigned short* __restrict__ w1b, unsigned short* __restrict__ w2b) {
  int g = blockIdx.x * 256 + threadIdx.x;
  const float* src;
  unsigned short* dst;
  if (g < 40960) {                 // abuf
    int idx = g * 8, b = idx / 640, k = idx - b * 640;
    src = (k < 512) ? emb + (size_t)x[b] * 512 + k : ctxp + b * 128 + (k - 512);
    dst = abuf + idx;
  } else if (g < 49152) {          // a2buf h_prev part (cols 512..639)
    int q = (g - 40960) * 8, b = q >> 7, d = q & 127;
    src = hprev + b * 128 + d;
    dst = a2buf + b * 640 + 512 + d;
  } else if (g < 90112) {          // w1b (W1w is contiguous [512][640])
    int idx = (g - 49152) * 8;
    src = W1w + idx;
    dst = w1b + idx;
  } else {                         // w2b = [Wih | Whh]
    int idx = (g - 90112) * 8, f = idx / 640, k = idx - f * 640;
    src = (k < 512) ? Wih + f * 512 + k : Whh + f * 128 + (k - 512);
    dst = w2b + idx;
  }
  f32x4 w0 = *(const f32x4*)src;
  f32x4 w1 = *(const f32x4*)(src + 4);
  *(s16x8*)&dst[0] = pk8(w0, w1);
}

// ---------------------------------------------------------------------------
// K1mm: x1(bf16, into a2buf cols 0..511) = abuf @ w1b^T + W1_b.
// k7-v6 template, M=512 N=512 K=640 (10 BK=64 steps), grid = 16 blocks.
// ---------------------------------------------------------------------------
__global__ __launch_bounds__(256) void k1mm(
    const unsigned short* __restrict__ abuf, const unsigned short* __restrict__ w1b,
    const float* __restrict__ W1b, unsigned short* __restrict__ a2buf) {
  __shared__ char smem[33280];
  unsigned short* Al = (unsigned short*)smem;
  unsigned short* Bl = (unsigned short*)(smem + 16384);
  const int bx = blockIdx.x;
  const int rp = bx & 3, cp = bx >> 2;
  const int r0 = rp * 128, c0 = cp * 128;
  const int tid = threadIdx.x;
  const int wv = tid >> 6, lane = tid & 63;
  const int lm = lane & 15, lg = lane >> 4;
  const int rh2 = wv >> 1, ch = wv & 1;

  const f32x4 zf4 = {0.f, 0.f, 0.f, 0.f};
  f32x4 acc[4][4];
#pragma unroll
  for (int m = 0; m < 4; ++m)
#pragma unroll
    for (int nf = 0; nf < 4; ++nf) acc[m][nf] = zf4;

  for (int ks = 0; ks < 10; ++ks) {
#pragma unroll
    for (int i = 0; i < 4; ++i) {
      int fi = wv * 4 + i;
      int rt = fi >> 1, kf = fi & 1;
      const unsigned short* sa =
          abuf + (r0 + rt * 16 + lm) * 640 + ks * 64 + kf * 32 + lg * 8;
      gload_lds16(sa, &Al[fi * 512 + lane * 8]);
      const unsigned short* sb =
          w1b + (c0 + rt * 16 + lm) * 640 + ks * 64 + kf * 32 + lg * 8;
      gload_lds16(sb, &Bl[fi * 512 + lane * 8]);
    }
    __syncthreads();
#pragma unroll
    for (int kf = 0; kf < 2; ++kf) {
      s16x8 a[4];
#pragma unroll
      for (int m = 0; m < 4; ++m)
        a[m] = *(const s16x8*)&Al[(((rh2 * 4 + m) * 2) + kf) * 512 + lane * 8];
#pragma unroll
      for (int nf = 0; nf < 4; ++nf) {
        s16x8 bfr = *(const s16x8*)&Bl[(((ch * 4 + nf) * 2) + kf) * 512 + lane * 8];
#pragma unroll
        for (int m = 0; m < 4; ++m)
          acc[m][nf] = __builtin_amdgcn_mfma_f32_16x16x32_bf16(a[m], bfr, acc[m][nf], 0, 0, 0);
      }
    }
    __syncthreads();
  }

  const int cw0 = c0 + ch * 64;
  float bias[4];
#pragma unroll
  for (int nf = 0; nf < 4; ++nf)
    bias[nf] = W1b[cw0 + nf * 16 + lm];

  float* T = (float*)smem + wv * 2080;
  const int rq = lane >> 4, cq = lane & 15;
#pragma unroll
  for (int p = 0; p < 2; ++p) {
#pragma unroll
    for (int mm = 0; mm < 2; ++mm) {
      int m = p * 2 + mm;
#pragma unroll
      for (int nf = 0; nf < 4; ++nf)
#pragma unroll
        for (int r = 0; r < 4; ++r)
          T[(mm * 16 + lg * 4 + r) * 65 + nf * 16 + lm] = acc[m][nf][r] + bias[nf];
    }
#pragma unroll
    for (int it = 0; it < 8; ++it) {
      int trow = it * 4 + rq;
      f32x4 vv = *(const f32x4*)&T[trow * 65 + cq * 4];
      s16x4 hb;
      hb[0] = f2bf(vv[0]); hb[1] = f2bf(vv[1]); hb[2] = f2bf(vv[2]); hb[3] = f2bf(vv[3]);
      int orow = r0 + rh2 * 64 + p * 32 + trow;
      *(s16x4*)&a2buf[orow * 640 + cw0 + cq * 4] = hb;
    }
  }
}

// ---------------------------------------------------------------------------
// K2mm: gates(f32) = a2buf @ w2b^T + b_ih + b_hh. Same template; f32 epilogue.
// ---------------------------------------------------------------------------
__global__ __launch_bounds__(256) void k2mm(
    const unsigned short* __restrict__ a2buf, const unsigned short* __restrict__ w2b,
    const float* __restrict__ bih, const float* __restrict__ bhh,
    float* __restrict__ gates) {
  __shared__ char smem[33280];
  unsigned short* Al = (unsigned short*)smem;
  unsigned short* Bl = (unsigned short*)(smem + 16384);
  const int bx = blockIdx.x;
  const int rp = bx & 3, cp = bx >> 2;
  const int r0 = rp * 128, c0 = cp * 128;
  const int tid = threadIdx.x;
  const int wv = tid >> 6, lane = tid & 63;
  const int lm = lane & 15, lg = lane >> 4;
  const int rh2 = wv >> 1, ch = wv & 1;

  const f32x4 zf4 = {0.f, 0.f, 0.f, 0.f};
  f32x4 acc[4][4];
#pragma unroll
  for (int m = 0; m < 4; ++m)
#pragma unroll
    for (int nf = 0; nf < 4; ++nf) acc[m][nf] = zf4;

  for (int ks = 0; ks < 10; ++ks) {
#pragma unroll
    for (int i = 0; i < 4; ++i) {
      int fi = wv * 4 + i;
      int rt = fi >> 1, kf = fi & 1;
      const unsigned short* sa =
          a2buf + (r0 + rt * 16 + lm) * 640 + ks * 64 + kf * 32 + lg * 8;
      gload_lds16(sa, &Al[fi * 512 + lane * 8]);
      const unsigned short* sb =
          w2b + (c0 + rt * 16 + lm) * 640 + ks * 64 + kf * 32 + lg * 8;
      gload_lds16(sb, &Bl[fi * 512 + lane * 8]);
    }
    __syncthreads();
#pragma unroll
    for (int kf = 0; kf < 2; ++kf) {
      s16x8 a[4];
#pragma unroll
      for (int m = 0; m < 4; ++m)
        a[m] = *(const s16x8*)&Al[(((rh2 * 4 + m) * 2) + kf) * 512 + lane * 8];
#pragma unroll
      for (int nf = 0; nf < 4; ++nf) {
        s16x8 bfr = *(const s16x8*)&Bl[(((ch * 4 + nf) * 2) + kf) * 512 + lane * 8];
#pragma unroll
        for (int m = 0; m < 4; ++m)
          acc[m][nf] = __builtin_amdgcn_mfma_f32_16x16x32_bf16(a[m], bfr, acc[m][nf], 0, 0, 0);
      }
    }
    __syncthreads();
  }

  const int cw0 = c0 + ch * 64;
  float bias[4];
#pragma unroll
  for (int nf = 0; nf < 4; ++nf) {
    int col = cw0 + nf * 16 + lm;
    bias[nf] = bih[col] + bhh[col];
  }

  float* T = (float*)smem + wv * 2080;
  const int rq = lane >> 4, cq = lane & 15;
#pragma unroll
  for (int p = 0; p < 2; ++p) {
#pragma unroll
    for (int mm = 0; mm < 2; ++mm) {
      int m = p * 2 + mm;
#pragma unroll
      for (int nf = 0; nf < 4; ++nf)
#pragma unroll
        for (int r = 0; r < 4; ++r)
          T[(mm * 16 + lg * 4 + r) * 65 + nf * 16 + lm] = acc[m][nf][r] + bias[nf];
    }
#pragma unroll
    for (int it = 0; it < 8; ++it) {
      int trow = it * 4 + rq;
      f32x4 vv = *(const f32x4*)&T[trow * 65 + cq * 4];
      int orow = r0 + rh2 * 64 + p * 32 + trow;
      *(f32x4*)&gates[(size_t)orow * 512 + cw0 + cq * 4] = vv;
    }
  }
}

// ---------------------------------------------------------------------------
// K3: LSTM cell + dec_f; also writes h (bf16) into hc_bf[b][0..127].
// ---------------------------------------------------------------------------
__global__ __launch_bounds__(128) void k3_lstm(
    const float* __restrict__ gates, const float* __restrict__ cprev,
    const float* __restrict__ Wsw, const float* __restrict__ Wsb,
    float* __restrict__ out_h, float* __restrict__ out_c,
    float* __restrict__ decf, unsigned short* __restrict__ hc_bf) {
  __shared__ float st[256];
  int b = blockIdx.x, d = threadIdx.x;
  const float* g = gates + b * 512;
  float iv = sigmoid_f(g[d]);
  float fv = sigmoid_f(g[128 + d]);
  float gv = tanh_f(g[256 + d]);
  float ov = sigmoid_f(g[384 + d]);
  float c = fv * cprev[b * 128 + d] + iv * gv;
  float h = ov * tanh_f(c);
  out_h[b * 128 + d] = h;
  out_c[b * 128 + d] = c;
  hc_bf[b * 256 + d] = (unsigned short)f2bf(h);
  st[d] = h; st[128 + d] = c;
  __syncthreads();
  float acc = Wsb[d];
  const float* wr = Wsw + d * 256;
#pragma unroll 4
  for (int k = 0; k < 256; ++k) acc += st[k] * wr[k];
  decf[b * 128 + d] = acc;
}

// ---------------------------------------------------------------------------
// K45 v4 (R14 version, REVERTED from split-T): fused e_t + softmax + ctx;
// ctx accumulated in the chunk loop with E1-shift weights; 512 blocks x 512.
// R15 post-mortem: split-T failed because VGPR (not block count) caps waves
// at 20/CU; splitting only doubled Wh-staging traffic and halved prefetch.
// ---------------------------------------------------------------------------
__global__ __launch_bounds__(512) void k45_attn(
    const float* __restrict__ h_i, const unsigned short* __restrict__ bw,
    const float* __restrict__ decf, const float* __restrict__ cov,
    const float* __restrict__ Wcw, const float* __restrict__ Vw,
    float* __restrict__ a_t, float* __restrict__ cov_out,
    float* __restrict__ ctx_out, unsigned short* __restrict__ hc_bf) {
  __shared__ unsigned short whl[16384];   // 32 KB frag-linear Wh
  __shared__ float sm[512];
  __shared__ float red[8][128];
  __shared__ float wred[8];
  __shared__ float dls[128], vls[128], wls[128];
  const int b = blockIdx.x;
  const int tid = threadIdx.x;
  const int wv = tid >> 6, lane = tid & 63;
  const int lm = lane & 15, lg = lane >> 4;
  const int t0w = wv * 64;

#pragma unroll
  for (int i = 0; i < 4; ++i)
    gload_lds16(&bw[(tid + i * 512) * 8], &whl[(tid + i * 512) * 8]);
  if (tid < 128) {
    dls[tid] = decf[b * 128 + tid];
    vls[tid] = Vw[tid];
    wls[tid] = Wcw[tid];
  }
  __syncthreads();   // drains vmcnt incl. global_load_lds

  // E1 = ||Vw||_1 : bit-identical on every lane/wave/block
  const volatile float* vlp = vls;
  const volatile float* dlp = dls;
  const volatile float* wlp = wls;
  float E1 = 0.f;
#pragma unroll
  for (int nf = 0; nf < 8; ++nf) E1 += fabsf(vlp[nf * 16 + lm]);
  E1 += __shfl_xor(E1, 1); E1 += __shfl_xor(E1, 2);
  E1 += __shfl_xor(E1, 4); E1 += __shfl_xor(E1, 8);

  const f32x4 zf4 = {0.f, 0.f, 0.f, 0.f};
  const float* abase = h_i + ((size_t)(b * 512 + t0w + lm)) * 128 + lg * 8;

  f32x4 r0, r1, r2, r3, r4, r5, r6, r7;   // raw chunk buffer
  f32x4 cv_raw;
  f32x4 c0 = zf4, c1 = zf4, c2 = zf4, c3 = zf4;   // ctx accumulators
  f32x4 c4 = zf4, c5 = zf4, c6 = zf4, c7 = zf4;
#define K45_LOADC(c)                                            \
  do {                                                          \
    const float* p_ = abase + (size_t)(c) * 16 * 128;           \
    r0 = *(const f32x4*)(p_ + 0);   r1 = *(const f32x4*)(p_ + 4);   \
    r2 = *(const f32x4*)(p_ + 32);  r3 = *(const f32x4*)(p_ + 36);  \
    r4 = *(const f32x4*)(p_ + 64);  r5 = *(const f32x4*)(p_ + 68);  \
    r6 = *(const f32x4*)(p_ + 96);  r7 = *(const f32x4*)(p_ + 100); \
    cv_raw = *(const f32x4*)&cov[b * 512 + t0w + (c) * 16 + lg * 4];\
  } while (0)
#define K45_ACC(ca, cb, pk)                                         \
  do {                                                              \
    u32x4 q_ = __builtin_bit_cast(u32x4, pk);                       \
    ca[0] += w * bitsf(q_[0] << 16); ca[1] += w * bitsf(q_[0] & 0xFFFF0000u); \
    ca[2] += w * bitsf(q_[1] << 16); ca[3] += w * bitsf(q_[1] & 0xFFFF0000u); \
    cb[0] += w * bitsf(q_[2] << 16); cb[1] += w * bitsf(q_[2] & 0xFFFF0000u); \
    cb[2] += w * bitsf(q_[3] << 16); cb[3] += w * bitsf(q_[3] & 0xFFFF0000u); \
  } while (0)

  K45_LOADC(0);
#pragma unroll
  for (int c = 0; c < 4; ++c) {
    s16x8 pk0 = pk8(r0, r1), pk1 = pk8(r2, r3);
    s16x8 pk2 = pk8(r4, r5), pk3 = pk8(r6, r7);
    f32x4 cov4 = cv_raw;
    if (c < 3) K45_LOADC(c + 1);  // next chunk in flight during compute

    float e4[4] = {0.f, 0.f, 0.f, 0.f};
#pragma unroll
    for (int nf = 0; nf < 8; ++nf) {
      float dv = dlp[nf * 16 + lm];
      float vw = vlp[nf * 16 + lm];
      float wc = wlp[nf * 16 + lm];
      s16x8 b0_ = *(const s16x8*)&whl[((nf * 4 + 0) * 64 + lane) * 8];
      s16x8 b1_ = *(const s16x8*)&whl[((nf * 4 + 1) * 64 + lane) * 8];
      s16x8 b2_ = *(const s16x8*)&whl[((nf * 4 + 2) * 64 + lane) * 8];
      s16x8 b3_ = *(const s16x8*)&whl[((nf * 4 + 3) * 64 + lane) * 8];
      f32x4 cc = zf4;
      cc = __builtin_amdgcn_mfma_f32_16x16x32_bf16(pk0, b0_, cc, 0, 0, 0);
      cc = __builtin_amdgcn_mfma_f32_16x16x32_bf16(pk1, b1_, cc, 0, 0, 0);
      cc = __builtin_amdgcn_mfma_f32_16x16x32_bf16(pk2, b2_, cc, 0, 0, 0);
      cc = __builtin_amdgcn_mfma_f32_16x16x32_bf16(pk3, b3_, cc, 0, 0, 0);
#pragma unroll
      for (int r = 0; r < 4; ++r) {
        float v = cc[r] + dv + cov4[r] * wc;
        e4[r] += vw * tanh_f(v);
      }
    }
    // allreduce over the 16 d-column lanes (result identical on all lanes)
#pragma unroll
    for (int i = 0; i < 4; ++i) {
      float v = e4[i];
      v += __shfl_xor(v, 1); v += __shfl_xor(v, 2);
      v += __shfl_xor(v, 4); v += __shfl_xor(v, 8);
      e4[i] = v;
    }
    if (lm == 0) {
#pragma unroll
      for (int r = 0; r < 4; ++r)
        sm[t0w + c * 16 + lg * 4 + r] = e4[r];
    }
    // w for THIS lane's row (t = c*16 + lm): e lives on lg group (lm>>2)
    int src = (lm >> 2) << 4;
    float s0 = __shfl(e4[0], src), s1 = __shfl(e4[1], src);
    float s2 = __shfl(e4[2], src), s3 = __shfl(e4[3], src);
    int rr = lm & 3;
    float ev = rr == 0 ? s0 : (rr == 1 ? s1 : (rr == 2 ? s2 : s3));
    float w = exp2f((ev - E1) * L2E);
    K45_ACC(c0, c1, pk0);
    K45_ACC(c2, c3, pk1);
    K45_ACC(c4, c5, pk2);
    K45_ACC(c6, c7, pk3);
  }
#undef K45_LOADC
#undef K45_ACC

  // reduce ctx over the 16 rows held across lm lanes (componentwise butterfly)
#define BFLY(x) { x += __shfl_xor(x, 1); x += __shfl_xor(x, 2); \
                  x += __shfl_xor(x, 4); x += __shfl_xor(x, 8); }
#pragma unroll
  for (int j = 0; j < 4; ++j) {
    BFLY(c0[j]); BFLY(c1[j]); BFLY(c2[j]); BFLY(c3[j]);
    BFLY(c4[j]); BFLY(c5[j]); BFLY(c6[j]); BFLY(c7[j]);
  }
#undef BFLY
  if (lm == 0) {
    float* rw = &red[wv][lg * 8];
#pragma unroll
    for (int j = 0; j < 4; ++j) {
      rw[j] = c0[j];       rw[4 + j] = c1[j];
      rw[32 + j] = c2[j];  rw[36 + j] = c3[j];
      rw[64 + j] = c4[j];  rw[68 + j] = c5[j];
      rw[96 + j] = c6[j];  rw[100 + j] = c7[j];
    }
  }
  __syncthreads();

  // softmax (shifted by E1 -- shift-invariant, no block max needed)
  float e = sm[tid];
  float w2 = exp2f((e - E1) * L2E);
  float s = w2;
  for (int off = 32; off; off >>= 1) s += __shfl_xor(s, off);
  if (lane == 0) wred[wv] = s;
  __syncthreads();
  float S1 = 0.f;
#pragma unroll
  for (int i = 0; i < 8; ++i) S1 += wred[i];
  float rS = __builtin_amdgcn_rcpf(S1);
  float a = w2 * rS;
  a_t[b * 512 + tid] = a;
  cov_out[b * 512 + tid] = cov[b * 512 + tid] + a;
  if (tid < 128) {
    float sa = 0.f;
#pragma unroll
    for (int g = 0; g < 8; ++g) sa += red[g][tid];
    float cx = sa * rS;
    ctx_out[b * 128 + tid] = cx;
    hc_bf[b * 256 + 128 + tid] = (unsigned short)f2bf(cx);
  }
}

// ---------------------------------------------------------------------------
// K6a: pv1(bf16) = hc_bf @ v1bh^T + V1_b  (M=512, N=384, K=256).
// ---------------------------------------------------------------------------
__global__ __launch_bounds__(256) void k6a_pv1(
    const unsigned short* __restrict__ hc_bf, const unsigned short* __restrict__ v1bh,
    const float* __restrict__ V1b, unsigned short* __restrict__ pv1bf) {
  __shared__ char smem[33280];
  unsigned short* Al = (unsigned short*)smem;
  unsigned short* Bl = (unsigned short*)(smem + 16384);
  const int bx = blockIdx.x;
  const int rp = bx & 3, cp = bx >> 2;     // cp 0..2
  const int r0 = rp * 128, c0 = cp * 128;
  const int tid = threadIdx.x;
  const int wv = tid >> 6, lane = tid & 63;
  const int lm = lane & 15, lg = lane >> 4;
  const int rh2 = wv >> 1, ch = wv & 1;

  const f32x4 zf4 = {0.f, 0.f, 0.f, 0.f};
  f32x4 acc[4][4];
#pragma unroll
  for (int m = 0; m < 4; ++m)
#pragma unroll
    for (int nf = 0; nf < 4; ++nf) acc[m][nf] = zf4;

  for (int ks = 0; ks < 4; ++ks) {
#pragma unroll
    for (int i = 0; i < 4; ++i) {
      int fi = wv * 4 + i;
      int rt = fi >> 1, kf = fi & 1;
      const unsigned short* sa =
          hc_bf + (r0 + rt * 16 + lm) * 256 + ks * 64 + kf * 32 + lg * 8;
      gload_lds16(sa, &Al[fi * 512 + lane * 8]);
      const unsigned short* sb =
          v1bh + (c0 + rt * 16 + lm) * 256 + ks * 64 + kf * 32 + lg * 8;
      gload_lds16(sb, &Bl[fi * 512 + lane * 8]);
    }
    __syncthreads();
#pragma unroll
    for (int kf = 0; kf < 2; ++kf) {
      s16x8 a[4];
#pragma unroll
      for (int m = 0; m < 4; ++m)
        a[m] = *(const s16x8*)&Al[(((rh2 * 4 + m) * 2) + kf) * 512 + lane * 8];
#pragma unroll
      for (int nf = 0; nf < 4; ++nf) {
        s16x8 bfr = *(const s16x8*)&Bl[(((ch * 4 + nf) * 2) + kf) * 512 + lane * 8];
#pragma unroll
        for (int m = 0; m < 4; ++m)
          acc[m][nf] = __builtin_amdgcn_mfma_f32_16x16x32_bf16(a[m], bfr, acc[m][nf], 0, 0, 0);
      }
    }
    __syncthreads();
  }

  const int cw0 = c0 + ch * 64;
  float bias[4];
#pragma unroll
  for (int nf = 0; nf < 4; ++nf)
    bias[nf] = V1b[cw0 + nf * 16 + lm];

  float* T = (float*)smem + wv * 2080;
  const int rq = lane >> 4, cq = lane & 15;
#pragma unroll
  for (int p = 0; p < 2; ++p) {
#pragma unroll
    for (int mm = 0; mm < 2; ++mm) {
      int m = p * 2 + mm;
#pragma unroll
      for (int nf = 0; nf < 4; ++nf)
#pragma unroll
        for (int r = 0; r < 4; ++r)
          T[(mm * 16 + lg * 4 + r) * 65 + nf * 16 + lm] = acc[m][nf][r] + bias[nf];
    }
#pragma unroll
    for (int it = 0; it < 8; ++it) {
      int trow = it * 4 + rq;
      f32x4 vv = *(const f32x4*)&T[trow * 65 + cq * 4];
      s16x4 hb;
      hb[0] = f2bf(vv[0]); hb[1] = f2bf(vv[1]); hb[2] = f2bf(vv[2]); hb[3] = f2bf(vv[3]);
      int orow = r0 + rh2 * 64 + p * 32 + trow;
      *(s16x4*)&pv1bf[orow * 384 + cw0 + cq * 4] = hb;
    }
  }
}

// ---------------------------------------------------------------------------
// K6b: p_gen = sigmoid([ctx|h|c|xe].W2 + b) ; attn_dist = (1-p_gen)*a_t
// ---------------------------------------------------------------------------
__global__ __launch_bounds__(256) void k6b_pgen(
    const float* __restrict__ out_h, const float* __restrict__ out_c,
    const float* __restrict__ ctx, const float* __restrict__ emb,
    const int* __restrict__ x, const float* __restrict__ W2w,
    const float* __restrict__ W2b, const float* __restrict__ a_t,
    float* __restrict__ pgen, float* __restrict__ attn_out) {
  __shared__ float cat[896];  // [ctx(128) | h(128) | c(128) | xe(512)]
  __shared__ float wr_[4];
  int b = blockIdx.x, tid = threadIdx.x;
  if (tid < 128) {
    cat[tid] = ctx[b * 128 + tid];
    cat[128 + tid] = out_h[b * 128 + tid];
  } else {
    int q = tid - 128;
    cat[256 + q] = out_c[b * 128 + q];
  }
  int xb = x[b];
  for (int k = tid; k < 512; k += 256) cat[384 + k] = emb[xb * 512 + k];
  __syncthreads();
  float p = 0.f;
  for (int k = tid; k < 896; k += 256) p += cat[k] * W2w[k];
  for (int off = 32; off; off >>= 1) p += __shfl_xor(p, off);
  if ((tid & 63) == 0) wr_[tid >> 6] = p;
  __syncthreads();
  float pg = sigmoid_f(wr_[0] + wr_[1] + wr_[2] + wr_[3] + W2b[0]);
  if (tid == 0) pgen[b] = pg;
  float om = 1.f - pg;
  attn_out[b * 512 + tid]       = om * a_t[b * 512 + tid];
  attn_out[b * 512 + 256 + tid] = om * a_t[b * 512 + 256 + tid];
}

// ---------------------------------------------------------------------------
// K7 v6 (m97-structure): logits(bf16) = pv1 @ v2bh^T + V2b -> aligned region
// in each d_out row slot. 940 blocks, 128x128 tile, BK=64, 4 waves.
// ---------------------------------------------------------------------------
__global__ __launch_bounds__(256) void k7_vocab(
    const unsigned short* __restrict__ pv1bf, const unsigned short* __restrict__ v2bh,
    const float* __restrict__ V2b, float* __restrict__ outF) {
  __shared__ char smem[33280];
  unsigned short* Al = (unsigned short*)smem;
  unsigned short* Bl = (unsigned short*)(smem + 16384);
  const int bx = blockIdx.x;
  const int rp = bx & 3, cp = bx >> 2;
  const int r0 = rp * 128, c0 = cp * 128;
  const int tid = threadIdx.x;
  const int wv = tid >> 6, lane = tid & 63;
  const int lm = lane & 15, lg = lane >> 4;
  const int rh2 = wv >> 1, ch = wv & 1;

  const f32x4 zf4 = {0.f, 0.f, 0.f, 0.f};
  f32x4 acc[4][4];
#pragma unroll
  for (int m = 0; m < 4; ++m)
#pragma unroll
    for (int nf = 0; nf < 4; ++nf) acc[m][nf] = zf4;

  for (int ks = 0; ks < 6; ++ks) {
#pragma unroll
    for (int i = 0; i < 4; ++i) {
      int fi = wv * 4 + i;
      int rt = fi >> 1, kf = fi & 1;
      const unsigned short* sa =
          pv1bf + (r0 + rt * 16 + lm) * 384 + ks * 64 + kf * 32 + lg * 8;
      gload_lds16(sa, &Al[fi * 512 + lane * 8]);
      const unsigned short* sb =
          v2bh + (size_t)(c0 + rt * 16 + lm) * 384 + ks * 64 + kf * 32 + lg * 8;
      gload_lds16(sb, &Bl[fi * 512 + lane * 8]);
    }
    __syncthreads();
#pragma unroll
    for (int kf = 0; kf < 2; ++kf) {
      s16x8 a[4];
#pragma unroll
      for (int m = 0; m < 4; ++m)
        a[m] = *(const s16x8*)&Al[(((rh2 * 4 + m) * 2) + kf) * 512 + lane * 8];
#pragma unroll
      for (int nf = 0; nf < 4; ++nf) {
        s16x8 bfr = *(const s16x8*)&Bl[(((ch * 4 + nf) * 2) + kf) * 512 + lane * 8];
#pragma unroll
        for (int m = 0; m < 4; ++m)
          acc[m][nf] = __builtin_amdgcn_mfma_f32_16x16x32_bf16(a[m], bfr, acc[m][nf], 0, 0, 0);
      }
    }
    __syncthreads();
  }

  const int cw0 = c0 + ch * 64;
  float bias[4];
#pragma unroll
  for (int nf = 0; nf < 4; ++nf) {
    int col = cw0 + nf * 16 + lm;
    bias[nf] = (col < VOC_) ? V2b[col] : 0.f;
  }

  float* T = (float*)smem + wv * 2080;
  const int rq = lane >> 4, cq = lane & 15;
#pragma unroll
  for (int p = 0; p < 2; ++p) {
#pragma unroll
    for (int mm = 0; mm < 2; ++mm) {
      int m = p * 2 + mm;
#pragma unroll
      for (int nf = 0; nf < 4; ++nf)
#pragma unroll
        for (int r = 0; r < 4; ++r)
          T[(mm * 16 + lg * 4 + r) * 65 + nf * 16 + lm] = acc[m][nf][r] + bias[nf];
    }
#pragma unroll
    for (int it = 0; it < 8; ++it) {
      int trow = it * 4 + rq;
      f32x4 vv = *(const f32x4*)&T[trow * 65 + cq * 4];
      s16x4 hb;
      hb[0] = f2bf(vv[0]); hb[1] = f2bf(vv[1]); hb[2] = f2bf(vv[2]); hb[3] = f2bf(vv[3]);
      int orow = r0 + rh2 * 64 + p * 32 + trow;
      unsigned short* dst = logit_row(outF, orow);
      *(s16x4*)&dst[cw0 + cq * 4] = hb;
    }
  }
}

// ---------------------------------------------------------------------------
// K7 fallback (R7 kernel, proven) -- used only if ws can't hold v2bh.
// ---------------------------------------------------------------------------
__global__ __launch_bounds__(256) void k7_vocab_fb(
    const unsigned short* __restrict__ pv1bf, const float* __restrict__ V2w,
    const float* __restrict__ V2b, float* __restrict__ outF) {
  __shared__ float lt[4][32 * 65];
  const int q = blockIdx.x;
  const int nb = ((q >> 4) << 3) + (q & 7);
  const int rh = (q >> 3) & 1;
  if (nb >= 469) return;
  const int v0 = nb * 64;
  const int tid = threadIdx.x;
  const int wv = tid >> 6, lane = tid & 63;
  const int lm = lane & 15, lg = lane >> 4;
  const int r0 = rh * 256 + wv * 64;

  const f32x4 zf4 = {0.f, 0.f, 0.f, 0.f};
  f32x4 acc[4][4];
#pragma unroll
  for (int m = 0; m < 4; ++m)
#pragma unroll
    for (int nf = 0; nf < 4; ++nf) acc[m][nf] = zf4;

  int vrow[4]; bool vok[4];
#pragma unroll
  for (int nf = 0; nf < 4; ++nf) {
    int v = v0 + nf * 16 + lm;
    vok[nf] = (v < VOC_);
    vrow[nf] = vok[nf] ? v : (VOC_ - 1);
  }

#pragma unroll
  for (int kf = 0; kf < 12; ++kf) {
    s16x8 afr[4];
#pragma unroll
    for (int m = 0; m < 4; ++m)
      afr[m] = *(const s16x8*)&pv1bf[(r0 + m * 16 + lm) * 384 + kf * 32 + lg * 8];
    s16x8 bfr[4];
#pragma unroll
    for (int nf = 0; nf < 4; ++nf) {
      const float* p = V2w + (size_t)vrow[nf] * 384 + kf * 32 + lg * 8;
      f32x4 w0 = *(const f32x4*)p;
      f32x4 w1 = *(const f32x4*)(p + 4);
      if (!vok[nf]) { w0 = zf4; w1 = zf4; }
      bfr[nf] = pk8(w0, w1);
    }
#pragma unroll
    for (int m = 0; m < 4; ++m)
#pragma unroll
      for (int nf = 0; nf < 4; ++nf)
        acc[m][nf] = __builtin_amdgcn_mfma_f32_16x16x32_bf16(afr[m], bfr[nf], acc[m][nf], 0, 0, 0);
  }

  float bias[4];
#pragma unroll
  for (int nf = 0; nf < 4; ++nf)
    bias[nf] = vok[nf] ? V2b[v0 + nf * 16 + lm] : 0.f;

  float* T = lt[wv];
  const int rq = lane >> 4, cq = lane & 15;
#pragma unroll
  for (int p = 0; p < 2; ++p) {
#pragma unroll
    for (int mm = 0; mm < 2; ++mm) {
      int m = p * 2 + mm;
#pragma unroll
      for (int nf = 0; nf < 4; ++nf)
#pragma unroll
        for (int r = 0; r < 4; ++r)
          T[(mm * 16 + lg * 4 + r) * 65 + nf * 16 + lm] = acc[m][nf][r] + bias[nf];
    }
#pragma unroll
    for (int it = 0; it < 8; ++it) {
      int trow = it * 4 + rq;
      f32x4 vv = *(const f32x4*)&T[trow * 65 + cq * 4];
      s16x4 hb;
      hb[0] = f2bf(vv[0]); hb[1] = f2bf(vv[1]); hb[2] = f2bf(vv[2]); hb[3] = f2bf(vv[3]);
      int orow = r0 + p * 32 + trow;
      unsigned short* dst = logit_row(outF, orow);
      *(s16x4*)&dst[v0 + cq * 4] = hb;
    }
  }
}

// ---------------------------------------------------------------------------
// K8: per-row softmax over bf16 logits, scale by p_gen, write f32 final_dist
// in place, zero 50 OOV cols, scatter-add attn_dist (workgroup atomics).
// ---------------------------------------------------------------------------
#define K8_IT 30  // ceil(VOC_/1024)

__global__ __launch_bounds__(1024) void k8_final(
    const float* __restrict__ pgen, const int* __restrict__ code_ext,
    const float* __restrict__ attn, float* __restrict__ outF) {
  __shared__ float lm_[16], ls_[16];
  const int b = blockIdx.x, tid = threadIdx.x;
  float* row = outF + (size_t)b * VEXT_;
  const unsigned short* lrow = logit_row(outF, b);

  float lv[K8_IT];
#pragma unroll
  for (int i = 0; i < K8_IT; ++i) {
    int v = tid + i * 1024;
    lv[i] = (v < VOC_) ? bf2f(lrow[v]) : -3.4e38f;
  }
  float m = lv[0];
#pragma unroll
  for (int i = 1; i < K8_IT; ++i) m = fmaxf(m, lv[i]);
  for (int off = 32; off; off >>= 1) m = fmaxf(m, __shfl_xor(m, off));
  if ((tid & 63) == 0) lm_[tid >> 6] = m;
  __syncthreads();
  float M = lm_[0];
#pragma unroll
  for (int i = 1; i < 16; ++i) M = fmaxf(M, lm_[i]);
  float s = 0.f;
#pragma unroll
  for (int i = 0; i < K8_IT; ++i) {
    lv[i] = exp2f((lv[i] - M) * L2E);
    s += lv[i];
  }
  for (int off = 32; off; off >>= 1) s += __shfl_xor(s, off);
  if ((tid & 63) == 0) ls_[tid >> 6] = s;
  __syncthreads();
  float S = 0.f;
#pragma unroll
  for (int i = 0; i < 16; ++i) S += ls_[i];
  float pm = pgen[b] / S;
#pragma unroll
  for (int i = 0; i < K8_IT; ++i) {
    int v = tid + i * 1024;
    if (v < VOC_) row[v] = pm * lv[i];
  }
  if (tid < 50) row[VOC_ + tid] = 0.f;
  __syncthreads();  // drains vmcnt: all row stores are at the local L2
  if (tid < 512) {
    int idx = code_ext[b * 512 + tid];
    __hip_atomic_fetch_add(&row[idx], attn[b * 512 + tid],
                           __ATOMIC_RELAXED, __HIP_MEMORY_SCOPE_WORKGROUP);
  }
}

// ---------------------------------------------------------------------------
extern "C" void kernel_launch(void* const* d_in, const int* in_sizes, int n_in,
                              void* d_out, int out_size, void* d_ws, size_t ws_size,
                              hipStream_t stream) {
  (void)in_sizes; (void)n_in; (void)out_size;
  const float* h_i    = (const float*)d_in[0];
  const float* h_prev = (const float*)d_in[1];
  const float* c_prev = (const float*)d_in[2];
  const float* ctxp   = (const float*)d_in[3];
  const float* cov    = (const float*)d_in[4];
  const float* emb    = (const float*)d_in[5];
  const float* Wih    = (const float*)d_in[6];
  const float* Whh    = (const float*)d_in[7];
  const float* bih    = (const float*)d_in[8];
  const float* bhh    = (const float*)d_in[9];
  const float* W1w    = (const float*)d_in[10];
  const float* W1b    = (const float*)d_in[11];
  const float* W2w    = (const float*)d_in[12];
  const float* W2b    = (const float*)d_in[13];
  const float* V1w    = (const float*)d_in[14];
  const float* V1b    = (const float*)d_in[15];
  const float* V2w    = (const float*)d_in[16];
  const float* V2b    = (const float*)d_in[17];
  const float* Whw    = (const float*)d_in[18];
  const float* Wsw    = (const float*)d_in[19];
  const float* Wsb    = (const float*)d_in[20];
  const float* Wcw    = (const float*)d_in[21];
  const float* Vw     = (const float*)d_in[22];
  const int*   x      = (const int*)d_in[23];
  const int*   code   = (const int*)d_in[24];

  float* ws = (float*)d_ws;
  // ws map (floats). Temporal aliasing: w1b/w2b (dead after k1mm/k2mm)
  // overlap the a_t region, which is first written by k45 (later). Safe.
  unsigned short* abuf  = (unsigned short*)(ws);            // 0      .. 163840
  unsigned short* a2buf = (unsigned short*)(ws + 163840);   // 163840 .. 327680
  float* gates = ws + 327680;                               // 327680 .. 589824
  float* decf  = ws + 589824;                               // 589824 .. 655360
  unsigned short* bw    = (unsigned short*)(ws + 655360);   // 655360 .. 663552
  unsigned short* hc_bf = (unsigned short*)(ws + 663552);   // 663552 .. 729088
  unsigned short* v1bh  = (unsigned short*)(ws + 729088);   // 729088 .. 778240
  unsigned short* w1b   = (unsigned short*)(ws + 778240);   // ..942080 (dead->a_t)
  unsigned short* w2b   = (unsigned short*)(ws + 942080);   // ..1105920 (dead)
  float* a_t   = ws + 851968;        // 851968 .. 1114112 (written by k45)
  unsigned short* pv1bf = (unsigned short*)(ws + 1114112);  // 196608 shorts
  float* pgen  = ws + 1212416;       // 512
  unsigned short* v2bh = (unsigned short*)(ws + 1212928);   // 11,550,720 shorts
  const size_t WS_NEEDED = (size_t)(1212928 + 5775360) * 4;
  const bool use_v6 = (ws_size >= WS_NEEDED);

  float* outF  = (float*)d_out;                    // final_dist 512 x 30051
  float* attn  = outF + (size_t)512 * VEXT_;       // 262144
  float* o_h   = attn + 262144;                    // 65536
  float* o_c   = o_h + 65536;                      // 65536
  float* o_cov = o_c + 65536;                      // 262144
  float* o_ctx = o_cov + 262144;                   // 65536

  k0_prep32<<<1, 256, 0, stream>>>(Whw, bw);
  if (use_v6) k0b_prepv2h<<<5640, 256, 0, stream>>>(V2w, v2bh);
  k0c_prepv1<<<48, 256, 0, stream>>>(V1w, v1bh);
  k0d_prep12<<<512, 256, 0, stream>>>(emb, x, ctxp, h_prev, W1w, Wih, Whh,
                                      abuf, a2buf, w1b, w2b);
  k1mm<<<16, 256, 0, stream>>>(abuf, w1b, W1b, a2buf);
  k2mm<<<16, 256, 0, stream>>>(a2buf, w2b, bih, bhh, gates);
  k3_lstm<<<512, 128, 0, stream>>>(gates, c_prev, Wsw, Wsb, o_h, o_c, decf, hc_bf);
  k45_attn<<<512, 512, 0, stream>>>(h_i, bw, decf, cov, Wcw, Vw, a_t, o_cov,
                                    o_ctx, hc_bf);
  k6a_pv1<<<12, 256, 0, stream>>>(hc_bf, v1bh, V1b, pv1bf);
  k6b_pgen<<<512, 256, 0, stream>>>(o_h, o_c, o_ctx, emb, x, W2w, W2b, a_t,
                                    pgen, attn);
  if (use_v6)
    k7_vocab<<<940, 256, 0, stream>>>(pv1bf, v2bh, V2b, outF);
  else
    k7_vocab_fb<<<944, 256, 0, stream>>>(pv1bf, V2w, V2b, outF);
  k8_final<<<512, 1024, 0, stream>>>(pgen, code, attn, outF);
}